// Round 2
// baseline (657.153 us; speedup 1.0000x reference)
//
#include <hip/hip_runtime.h>
#include <math.h>

// GCN 2-layer forward on MI355X.
// Pipeline: count in-degree -> scan -> CSR fill -> m1=(x@W1)*dinv ->
//           agg1 (gather + relu + @W2 fused) -> agg2 (gather + bias + mask)
// NOTE: harness delivers integer inputs as int32 (edge_index is const int*).

constexpr int N   = 100000;
constexpr int E   = 3200000;
constexpr int FIN = 128;
constexpr int FH  = 64;

#define SCAN_BS 1024
constexpr int NB_SCAN = (N + SCAN_BS - 1) / SCAN_BS;  // 98

__global__ void k_zero_cnt(int* __restrict__ cnt) {
  int i = blockIdx.x * blockDim.x + threadIdx.x;
  if (i < N) cnt[i] = 0;
}

__global__ void k_count(const int* __restrict__ dstA, int* __restrict__ cnt) {
  int i = blockIdx.x * blockDim.x + threadIdx.x;
  int stride = gridDim.x * blockDim.x;
  for (; i < E; i += stride) atomicAdd(&cnt[dstA[i]], 1);
}

__global__ void k_blocksum(const int* __restrict__ cnt, int* __restrict__ bsum) {
  __shared__ int sh[SCAN_BS];
  int i = blockIdx.x * SCAN_BS + threadIdx.x;
  sh[threadIdx.x] = (i < N) ? cnt[i] : 0;
  __syncthreads();
  for (int off = SCAN_BS / 2; off > 0; off >>= 1) {
    if (threadIdx.x < off) sh[threadIdx.x] += sh[threadIdx.x + off];
    __syncthreads();
  }
  if (threadIdx.x == 0) bsum[blockIdx.x] = sh[0];
}

__global__ void k_scanbsum(int* __restrict__ bsum) {
  if (threadIdx.x == 0 && blockIdx.x == 0) {
    int s = 0;
    for (int b = 0; b < NB_SCAN; ++b) { int v = bsum[b]; bsum[b] = s; s += v; }
  }
}

__global__ void k_scan3(const int* __restrict__ cnt, const int* __restrict__ bsum,
                        int* __restrict__ rowptr, int* __restrict__ cursor,
                        float* __restrict__ dinv) {
  __shared__ int sh[SCAN_BS];
  int i = blockIdx.x * SCAN_BS + threadIdx.x;
  int v = (i < N) ? cnt[i] : 0;
  sh[threadIdx.x] = v;
  __syncthreads();
  // Hillis-Steele inclusive scan (double-barrier form)
  for (int off = 1; off < SCAN_BS; off <<= 1) {
    int t = (threadIdx.x >= off) ? sh[threadIdx.x - off] : 0;
    __syncthreads();
    sh[threadIdx.x] += t;
    __syncthreads();
  }
  if (i < N) {
    int incl = sh[threadIdx.x] + bsum[blockIdx.x];
    rowptr[i + 1] = incl;
    cursor[i] = incl - v;          // exclusive prefix = segment start
    if (i == 0) rowptr[0] = 0;
    dinv[i] = 1.0f / sqrtf((float)(v + 1));  // deg includes self-loop, always >=1
  }
}

__global__ void k_fill(const int* __restrict__ srcA, const int* __restrict__ dstA,
                       int* __restrict__ cursor, int* __restrict__ csr_src) {
  int i = blockIdx.x * blockDim.x + threadIdx.x;
  int stride = gridDim.x * blockDim.x;
  for (; i < E; i += stride) {
    int s = srcA[i];
    int d = dstA[i];
    int p = atomicAdd(&cursor[d], 1);
    csr_src[p] = s;
  }
}

// m1[n, f] = (x[n,:] @ W1[:,f]) * dinv[n]
__global__ __launch_bounds__(256) void k_gemm1(const float* __restrict__ x,
                                               const float* __restrict__ W1,
                                               const float* __restrict__ dinv,
                                               float* __restrict__ m1) {
  __shared__ float W1s[FIN * FH];  // 32 KB
  for (int i = threadIdx.x; i < FIN * FH; i += 256) W1s[i] = W1[i];
  __syncthreads();
  int lane = threadIdx.x & 63;
  int w = threadIdx.x >> 6;
  for (int grp = blockIdx.x; grp * 4 < N; grp += gridDim.x) {
    int node = grp * 4 + w;
    if (node >= N) continue;
    int nu = __builtin_amdgcn_readfirstlane(node);  // force scalar x-row loads
    const float* xr = x + (size_t)nu * FIN;
    float a0 = 0.f, a1 = 0.f, a2 = 0.f, a3 = 0.f;
#pragma unroll
    for (int k = 0; k < FIN; k += 4) {
      a0 = fmaf(xr[k + 0], W1s[(k + 0) * FH + lane], a0);
      a1 = fmaf(xr[k + 1], W1s[(k + 1) * FH + lane], a1);
      a2 = fmaf(xr[k + 2], W1s[(k + 2) * FH + lane], a2);
      a3 = fmaf(xr[k + 3], W1s[(k + 3) * FH + lane], a3);
    }
    m1[(size_t)nu * FH + lane] = ((a0 + a1) + (a2 + a3)) * dinv[nu];
  }
}

// Conv1 aggregate (gather over CSR) + bias + relu + fused h@W2 -> m2 = h2*dinv
__global__ __launch_bounds__(256) void k_agg1(const float* __restrict__ m1,
                                              const int* __restrict__ rowptr,
                                              const int* __restrict__ csr_src,
                                              const float* __restrict__ dinv,
                                              const float* __restrict__ b1,
                                              const float* __restrict__ W2,
                                              float* __restrict__ m2) {
  int node = blockIdx.x * 4 + (threadIdx.x >> 6);
  if (node >= N) return;
  int lane = threadIdx.x & 63;
  int nu = __builtin_amdgcn_readfirstlane(node);
  int start = __builtin_amdgcn_readfirstlane(rowptr[nu]);
  int end   = __builtin_amdgcn_readfirstlane(rowptr[nu + 1]);
  float acc = m1[(size_t)nu * FH + lane];  // self-loop message (pre-scaled)
  for (int base = start; base < end; base += 64) {
    int cntE = min(64, end - base);
    int sv = (lane < cntE) ? csr_src[base + lane] : 0;  // one coalesced read of src ids
    float a0 = 0.f, a1 = 0.f;
    int j = 0;
    for (; j + 2 <= cntE; j += 2) {
      int s0 = __shfl(sv, j);
      int s1 = __shfl(sv, j + 1);
      a0 += m1[(size_t)s0 * FH + lane];
      a1 += m1[(size_t)s1 * FH + lane];
    }
    if (j < cntE) a0 += m1[(size_t)__shfl(sv, j) * FH + lane];
    acc += a0 + a1;
  }
  float dv = dinv[nu];
  float h = fmaxf(acc * dv + b1[lane], 0.f);
  // h @ W2 : two dot-products across the 64 lanes
  float p0 = h * W2[lane * 2 + 0];
  float p1 = h * W2[lane * 2 + 1];
#pragma unroll
  for (int off = 32; off > 0; off >>= 1) {
    p0 += __shfl_xor(p0, off);
    p1 += __shfl_xor(p1, off);
  }
  if (lane == 0) {
    m2[nu * 2 + 0] = p0 * dv;
    m2[nu * 2 + 1] = p1 * dv;
  }
}

// Conv2 aggregate + bias + generator mask
__global__ __launch_bounds__(256) void k_agg2(const float* __restrict__ m2,
                                              const int* __restrict__ rowptr,
                                              const int* __restrict__ csr_src,
                                              const float* __restrict__ dinv,
                                              const float* __restrict__ b2,
                                              const float* __restrict__ x,
                                              float* __restrict__ out) {
  int node = blockIdx.x * 4 + (threadIdx.x >> 6);
  if (node >= N) return;
  int lane = threadIdx.x & 63;
  int nu = __builtin_amdgcn_readfirstlane(node);
  int start = __builtin_amdgcn_readfirstlane(rowptr[nu]);
  int end   = __builtin_amdgcn_readfirstlane(rowptr[nu + 1]);
  float a0 = 0.f, a1 = 0.f;
  for (int e = start + lane; e < end; e += 64) {
    int s = csr_src[e];
    a0 += m2[s * 2 + 0];
    a1 += m2[s * 2 + 1];
  }
#pragma unroll
  for (int off = 32; off > 0; off >>= 1) {
    a0 += __shfl_xor(a0, off);
    a1 += __shfl_xor(a1, off);
  }
  if (lane == 0) {
    a0 += m2[nu * 2 + 0];  // self-loop
    a1 += m2[nu * 2 + 1];
    float dv = dinv[nu];
    float o0 = a0 * dv + b2[0];
    float o1 = a1 * dv + b2[1];
    float msk = (x[(size_t)nu * FIN] == 1.0f) ? 1.0f : 0.0f;
    out[nu * 2 + 0] = o0 * msk;
    out[nu * 2 + 1] = o1 * msk;
  }
}

extern "C" void kernel_launch(void* const* d_in, const int* in_sizes, int n_in,
                              void* d_out, int out_size, void* d_ws, size_t ws_size,
                              hipStream_t stream) {
  const float* x   = (const float*)d_in[0];
  const int*   ei  = (const int*)d_in[1];  // int inputs arrive as int32; [2, E] flat
  const float* W1  = (const float*)d_in[2];
  const float* b1  = (const float*)d_in[3];
  const float* W2  = (const float*)d_in[4];
  const float* b2  = (const float*)d_in[5];
  float*       out = (float*)d_out;

  char* w = (char*)d_ws;
  auto alloc = [&](size_t bytes) -> char* {
    char* p = w;
    w += (bytes + 255) & ~(size_t)255;
    return p;
  };
  int*   cnt     = (int*)alloc((size_t)N * 4);
  int*   rowptr  = (int*)alloc((size_t)(N + 1) * 4);
  int*   cursor  = (int*)alloc((size_t)N * 4);
  float* dinv    = (float*)alloc((size_t)N * 4);
  int*   bsum    = (int*)alloc((size_t)NB_SCAN * 4);
  int*   csr_src = (int*)alloc((size_t)E * 4);
  float* m1      = (float*)alloc((size_t)N * FH * 4);
  float* m2      = (float*)alloc((size_t)N * 2 * 4);

  const int* srcA = ei;      // edge_index[0]
  const int* dstA = ei + E;  // edge_index[1]

  k_zero_cnt<<<dim3((N + 255) / 256), dim3(256), 0, stream>>>(cnt);
  k_count<<<dim3(2048), dim3(256), 0, stream>>>(dstA, cnt);
  k_blocksum<<<dim3(NB_SCAN), dim3(SCAN_BS), 0, stream>>>(cnt, bsum);
  k_scanbsum<<<dim3(1), dim3(64), 0, stream>>>(bsum);
  k_scan3<<<dim3(NB_SCAN), dim3(SCAN_BS), 0, stream>>>(cnt, bsum, rowptr, cursor, dinv);
  k_fill<<<dim3(2048), dim3(256), 0, stream>>>(srcA, dstA, cursor, csr_src);
  k_gemm1<<<dim3(1024), dim3(256), 0, stream>>>(x, W1, dinv, m1);
  k_agg1<<<dim3((N + 3) / 4), dim3(256), 0, stream>>>(m1, rowptr, csr_src, dinv, b1, W2, m2);
  k_agg2<<<dim3((N + 3) / 4), dim3(256), 0, stream>>>(m2, rowptr, csr_src, dinv, b2, x, out);
}